// Round 1
// baseline (51.904 us; speedup 1.0000x reference)
//
#include <hip/hip_runtime.h>

// Bilinear warp via flow field.
// im:   [B=8, H=256, W=256, C=64] float32
// flow: [B, H, W, 2]              float32
// out:  [B, H, W, C]              float32
//
// Mapping: 16 lanes per output texel, each lane handles 4 channels (float4).
// Channels are innermost-contiguous -> each corner read is 16 lanes x 16B
// = 256B fully coalesced.

constexpr int Bc = 8, Hc = 256, Wc = 256, Cc = 64;

__global__ __launch_bounds__(256) void SWN_warp_kernel(
    const float* __restrict__ im,
    const float* __restrict__ flow,
    float* __restrict__ out)
{
    const int tid = blockIdx.x * 256 + threadIdx.x;
    const int p   = tid >> 4;        // texel index in [0, B*H*W)
    const int c4i = tid & 15;        // which float4 of the 64 channels

    const int w = p & (Wc - 1);
    const int h = (p >> 8) & (Hc - 1);
    const int b = p >> 16;

    // flow for this texel (16 lanes read the same 8B -> L1 broadcast)
    const float2 fl = *reinterpret_cast<const float2*>(flow + (size_t)p * 2);

    const float Hf = (float)Hc;
    const float Wf = (float)Wc;

    // normalized meshgrid, matching jnp.linspace(-1, 1, N)
    float gx = -1.0f + 2.0f * (float)w / (float)(Wc - 1);
    float gy = -1.0f + 2.0f * (float)h / (float)(Hc - 1);

    // reference op order
    float x = gx + fl.x / Hf;
    float y = gy + fl.y / Hf;
    x = (x + 1.0f) * Wf * 0.5f;
    y = (y + 1.0f) * Hf * 0.5f;

    const float fx0 = floorf(x);
    const float fy0 = floorf(y);
    int x0 = (int)fx0;
    int y0 = (int)fy0;
    int x1 = x0 + 1;
    int y1 = y0 + 1;

    const int mx = Hc - 1;  // reference clips both axes to H-1
    int x0c = min(max(x0, 0), mx);
    int x1c = min(max(x1, 0), mx);
    int y0c = min(max(y0, 0), mx);
    int y1c = min(max(y1, 0), mx);

    const float x0f = (float)x0c;
    const float x1f = (float)x1c;
    const float y0f = (float)y0c;
    const float y1f = (float)y1c;

    const float wa = (x1f - x) * (y1f - y);
    const float wb = (x1f - x) * (y - y0f);
    const float wcw = (x - x0f) * (y1f - y);
    const float wd = (x - x0f) * (y - y0f);

    const float4* imb = reinterpret_cast<const float4*>(
        im + (size_t)b * Hc * Wc * Cc);
    const int CV = Cc / 4;  // float4s per texel

    const float4 Ia = imb[(size_t)(y0c * Wc + x0c) * CV + c4i];
    const float4 Ib = imb[(size_t)(y1c * Wc + x0c) * CV + c4i];
    const float4 Ic = imb[(size_t)(y0c * Wc + x1c) * CV + c4i];
    const float4 Id = imb[(size_t)(y1c * Wc + x1c) * CV + c4i];

    float4 o;
    o.x = wa * Ia.x + wb * Ib.x + wcw * Ic.x + wd * Id.x;
    o.y = wa * Ia.y + wb * Ib.y + wcw * Ic.y + wd * Id.y;
    o.z = wa * Ia.z + wb * Ib.z + wcw * Ic.z + wd * Id.z;
    o.w = wa * Ia.w + wb * Ib.w + wcw * Ic.w + wd * Id.w;

    reinterpret_cast<float4*>(out)[(size_t)p * CV + c4i] = o;
}

extern "C" void kernel_launch(void* const* d_in, const int* in_sizes, int n_in,
                              void* d_out, int out_size, void* d_ws, size_t ws_size,
                              hipStream_t stream) {
    const float* im   = (const float*)d_in[0];
    const float* flow = (const float*)d_in[1];
    float* out        = (float*)d_out;

    // B*H*W texels * 16 threads each / 256 threads per block
    const int total_threads = Bc * Hc * Wc * 16;
    const int blocks = total_threads / 256;
    SWN_warp_kernel<<<blocks, 256, 0, stream>>>(im, flow, out);
}

// Round 3
// 47.244 us; speedup vs baseline: 1.0986x; 1.0986x over previous
//
#include <hip/hip_runtime.h>

// Bilinear warp via flow field.
// im:   [B=8, H=256, W=256, C=64] float32
// flow: [B, H, W, 2]              float32
// out:  [B, H, W, C]              float32
//
// Mapping: 8 lanes per output texel, each lane handles 8 channels (2x float4).
// Channels innermost-contiguous -> each corner read is 8 lanes x 32B = 256B
// fully coalesced. Output stores are nontemporal (write-once stream) so the
// 134MB write stream doesn't evict im's reuse window from L2.

constexpr int Bc = 8, Hc = 256, Wc = 256, Cc = 64;

// clang native vector type (HIP's float4 is a class -> rejected by
// __builtin_nontemporal_store)
typedef float v4f __attribute__((ext_vector_type(4)));
typedef float v2f __attribute__((ext_vector_type(2)));

__global__ __launch_bounds__(256) void SWN_warp_kernel(
    const float* __restrict__ im,
    const float* __restrict__ flow,
    float* __restrict__ out)
{
    const int tid = blockIdx.x * 256 + threadIdx.x;
    const int p   = tid >> 3;        // texel index in [0, B*H*W)
    const int c8i = tid & 7;         // which 32B chunk of the 64 channels

    const int w = p & (Wc - 1);
    const int h = (p >> 8) & (Hc - 1);
    const int b = p >> 16;

    // flow for this texel (8 lanes read the same 8B -> broadcast)
    const v2f fl = *reinterpret_cast<const v2f*>(flow + (size_t)p * 2);

    const float Hf = (float)Hc;
    const float Wf = (float)Wc;

    // normalized meshgrid, matching jnp.linspace(-1, 1, N)
    float gx = -1.0f + 2.0f * (float)w / (float)(Wc - 1);
    float gy = -1.0f + 2.0f * (float)h / (float)(Hc - 1);

    // reference op order
    float x = gx + fl.x / Hf;
    float y = gy + fl.y / Hf;
    x = (x + 1.0f) * Wf * 0.5f;
    y = (y + 1.0f) * Hf * 0.5f;

    const float fx0 = floorf(x);
    const float fy0 = floorf(y);
    int x0 = (int)fx0;
    int y0 = (int)fy0;
    int x1 = x0 + 1;
    int y1 = y0 + 1;

    const int mx = Hc - 1;  // reference clips both axes to H-1
    int x0c = min(max(x0, 0), mx);
    int x1c = min(max(x1, 0), mx);
    int y0c = min(max(y0, 0), mx);
    int y1c = min(max(y1, 0), mx);

    const float x0f = (float)x0c;
    const float x1f = (float)x1c;
    const float y0f = (float)y0c;
    const float y1f = (float)y1c;

    const float wa = (x1f - x) * (y1f - y);
    const float wb = (x1f - x) * (y - y0f);
    const float wcw = (x - x0f) * (y1f - y);
    const float wd = (x - x0f) * (y - y0f);

    const v4f* imb = reinterpret_cast<const v4f*>(
        im + (size_t)b * Hc * Wc * Cc);
    const int CV = Cc / 4;  // 16 float4s per texel

    // uint32 float4-indices within batch (max ~1M, fits easily)
    const unsigned ia = (unsigned)(y0c * Wc + x0c) * CV + c8i * 2;
    const unsigned ib = (unsigned)(y1c * Wc + x0c) * CV + c8i * 2;
    const unsigned ic = (unsigned)(y0c * Wc + x1c) * CV + c8i * 2;
    const unsigned id = (unsigned)(y1c * Wc + x1c) * CV + c8i * 2;

    const v4f Ia0 = imb[ia],     Ia1 = imb[ia + 1];
    const v4f Ib0 = imb[ib],     Ib1 = imb[ib + 1];
    const v4f Ic0 = imb[ic],     Ic1 = imb[ic + 1];
    const v4f Id0 = imb[id],     Id1 = imb[id + 1];

    v4f o0 = wa * Ia0 + wb * Ib0 + wcw * Ic0 + wd * Id0;
    v4f o1 = wa * Ia1 + wb * Ib1 + wcw * Ic1 + wd * Id1;

    v4f* outp = reinterpret_cast<v4f*>(out) + (size_t)p * CV + c8i * 2;
    __builtin_nontemporal_store(o0, outp);
    __builtin_nontemporal_store(o1, outp + 1);
}

extern "C" void kernel_launch(void* const* d_in, const int* in_sizes, int n_in,
                              void* d_out, int out_size, void* d_ws, size_t ws_size,
                              hipStream_t stream) {
    const float* im   = (const float*)d_in[0];
    const float* flow = (const float*)d_in[1];
    float* out        = (float*)d_out;

    // B*H*W texels * 8 threads each / 256 threads per block
    const int total_threads = Bc * Hc * Wc * 8;
    const int blocks = total_threads / 256;
    SWN_warp_kernel<<<blocks, 256, 0, stream>>>(im, flow, out);
}